// Round 1
// baseline (782.289 us; speedup 1.0000x reference)
//
#include <hip/hip_runtime.h>
#include <hip/hip_bf16.h>

// Problem constants (from setup_inputs): B=8, N=8192, S=2048, D1=128, D2=256
// mlp = [256, 128]; in_ch = 384. All fp32.
#define BATCH 8
#define NPTS  8192
#define SPTS  2048
#define D1C   128
#define D2C   256
#define C_IN  384
#define O0    256
#define O1    128
#define MROWS (BATCH * NPTS)   // 65536

// ---------------------------------------------------------------------------
// Kernel 1: 3-nearest-neighbor search + inverse-distance weights.
// One block = 256 query points of one batch. xyz2 (+ its squared norm) for the
// batch staged in LDS as float4.
// ---------------------------------------------------------------------------
__global__ __launch_bounds__(256) void nn3_kernel(
    const float* __restrict__ xyz1, const float* __restrict__ xyz2,
    int* __restrict__ idx3, float* __restrict__ wgt3)
{
    __shared__ float4 P[SPTS];
    const int b = blockIdx.y;
    const int n = blockIdx.x * 256 + threadIdx.x;

    const float* x2 = xyz2 + (size_t)b * SPTS * 3;
    for (int s = threadIdx.x; s < SPTS; s += 256) {
        float px = x2[s * 3 + 0];
        float py = x2[s * 3 + 1];
        float pz = x2[s * 3 + 2];
        P[s] = make_float4(px, py, pz, px * px + py * py + pz * pz);
    }
    __syncthreads();

    const float* q = xyz1 + ((size_t)b * NPTS + n) * 3;
    const float qx = q[0], qy = q[1], qz = q[2];
    const float qn = qx * qx + qy * qy + qz * qz;

    float d0 = 1e30f, d1 = 1e30f, d2 = 1e30f;
    int   i0 = 0,     i1 = 0,     i2 = 0;

    #pragma unroll 4
    for (int s = 0; s < SPTS; ++s) {
        float4 p = P[s];
        float dot = qx * p.x + qy * p.y + qz * p.z;
        // match reference formula: |q|^2 + |p|^2 - 2 q.p
        float d = (qn + p.w) - 2.0f * dot;
        if (d < d2) {
            if (d < d0)      { d2 = d1; i2 = i1; d1 = d0; i1 = i0; d0 = d; i0 = s; }
            else if (d < d1) { d2 = d1; i2 = i1; d1 = d;  i1 = s; }
            else             { d2 = d;  i2 = s; }
        }
    }

    float wa = 1.0f / (d0 + 1e-8f);
    float wb = 1.0f / (d1 + 1e-8f);
    float wc = 1.0f / (d2 + 1e-8f);
    float inv = 1.0f / (wa + wb + wc);
    wa *= inv; wb *= inv; wc *= inv;

    const int r = b * NPTS + n;
    idx3[r * 3 + 0] = i0;
    idx3[r * 3 + 1] = i1;
    idx3[r * 3 + 2] = i2;
    wgt3[r * 3 + 0] = wa;
    wgt3[r * 3 + 1] = wb;
    wgt3[r * 3 + 2] = wc;
}

// ---------------------------------------------------------------------------
// Kernel 2: GEMM0 with fused interpolation.
//   y0[m][o] = b0[o] + sum_k x[m][k] * w0[o][k]
//   x[m][k] = points1[m][k]                         (k < 128)
//           = sum_j w[m][j] * points2[b][idx[m][j]][k-128]   (k >= 128)
// 64x64 tile, BK=16, 256 threads, 4x4 accum per thread.
// Also accumulates per-channel sum / sumsq of (pre-BN) y0 for batch-norm.
// ---------------------------------------------------------------------------
__global__ __launch_bounds__(256) void gemm0_kernel(
    const float* __restrict__ points1, const float* __restrict__ points2,
    const int* __restrict__ idx3, const float* __restrict__ wgt3,
    const float* __restrict__ w0, const float* __restrict__ b0,
    float* __restrict__ y0, float* __restrict__ sum0, float* __restrict__ sq0)
{
    __shared__ float As[64][20];
    __shared__ float Bs[64][20];
    __shared__ int   sI[64][3];
    __shared__ float sW[64][3];
    __shared__ float red[16][64];

    const int t = threadIdx.x;
    const int rowBase = blockIdx.y * 64;
    const int colBase = blockIdx.x * 64;
    const int b = rowBase >> 13;          // rowBase / NPTS
    const int nBase = rowBase & (NPTS - 1);

    if (t < 64) {
        int row = rowBase + t;
        sI[t][0] = idx3[row * 3 + 0];
        sI[t][1] = idx3[row * 3 + 1];
        sI[t][2] = idx3[row * 3 + 2];
        sW[t][0] = wgt3[row * 3 + 0];
        sW[t][1] = wgt3[row * 3 + 1];
        sW[t][2] = wgt3[row * 3 + 2];
    }
    __syncthreads();

    const int tx = t & 15, ty = t >> 4;
    const int ar = t >> 2, ak4 = t & 3;   // staging: row, k-quad

    const float* p1row = points1 + (size_t)(b * NPTS + nBase + ar) * D1C;
    const float* p2b   = points2 + (size_t)b * SPTS * D2C;
    const int   gi0 = sI[ar][0], gi1 = sI[ar][1], gi2 = sI[ar][2];
    const float gw0 = sW[ar][0], gw1 = sW[ar][1], gw2 = sW[ar][2];
    const float* wrow = w0 + (size_t)(colBase + ar) * C_IN;

    float acc[4][4] = {};

    for (int kt = 0; kt < C_IN; kt += 16) {
        const int kg = kt + ak4 * 4;
        float4 av;
        if (kg < D1C) {
            av = *(const float4*)(p1row + kg);
        } else {
            const int k2 = kg - D1C;
            float4 a0 = *(const float4*)(p2b + gi0 * D2C + k2);
            float4 a1 = *(const float4*)(p2b + gi1 * D2C + k2);
            float4 a2 = *(const float4*)(p2b + gi2 * D2C + k2);
            av.x = gw0 * a0.x + gw1 * a1.x + gw2 * a2.x;
            av.y = gw0 * a0.y + gw1 * a1.y + gw2 * a2.y;
            av.z = gw0 * a0.z + gw1 * a1.z + gw2 * a2.z;
            av.w = gw0 * a0.w + gw1 * a1.w + gw2 * a2.w;
        }
        *(float4*)&As[ar][ak4 * 4] = av;
        *(float4*)&Bs[ar][ak4 * 4] = *(const float4*)(wrow + kg);
        __syncthreads();

        #pragma unroll
        for (int kk = 0; kk < 16; ++kk) {
            float a[4], bb[4];
            #pragma unroll
            for (int i = 0; i < 4; ++i) a[i] = As[ty * 4 + i][kk];
            #pragma unroll
            for (int j = 0; j < 4; ++j) bb[j] = Bs[tx * 4 + j][kk];
            #pragma unroll
            for (int i = 0; i < 4; ++i)
                #pragma unroll
                for (int j = 0; j < 4; ++j) acc[i][j] += a[i] * bb[j];
        }
        __syncthreads();
    }

    // bias (stats are on biased pre-BN y)
    float bias[4];
    #pragma unroll
    for (int j = 0; j < 4; ++j) bias[j] = b0[colBase + tx * 4 + j];
    #pragma unroll
    for (int i = 0; i < 4; ++i)
        #pragma unroll
        for (int j = 0; j < 4; ++j) acc[i][j] += bias[j];

    // write y0
    #pragma unroll
    for (int i = 0; i < 4; ++i) {
        int row = rowBase + ty * 4 + i;
        float4 o = make_float4(acc[i][0], acc[i][1], acc[i][2], acc[i][3]);
        *(float4*)(y0 + (size_t)row * O0 + colBase + tx * 4) = o;
    }

    // per-channel stats: reduce over the 64 rows of this tile, one atomic/col
    float cs[4], cq[4];
    #pragma unroll
    for (int j = 0; j < 4; ++j) {
        cs[j] = acc[0][j] + acc[1][j] + acc[2][j] + acc[3][j];
        cq[j] = acc[0][j] * acc[0][j] + acc[1][j] * acc[1][j]
              + acc[2][j] * acc[2][j] + acc[3][j] * acc[3][j];
    }
    #pragma unroll
    for (int j = 0; j < 4; ++j) red[ty][tx * 4 + j] = cs[j];
    __syncthreads();
    if (t < 64) {
        float s = 0.f;
        #pragma unroll
        for (int yy = 0; yy < 16; ++yy) s += red[yy][t];
        atomicAdd(&sum0[colBase + t], s);
    }
    __syncthreads();
    #pragma unroll
    for (int j = 0; j < 4; ++j) red[ty][tx * 4 + j] = cq[j];
    __syncthreads();
    if (t < 64) {
        float s = 0.f;
        #pragma unroll
        for (int yy = 0; yy < 16; ++yy) s += red[yy][t];
        atomicAdd(&sq0[colBase + t], s);
    }
}

// ---------------------------------------------------------------------------
// stats: scale = g * rsqrt(var + eps), shift = beta - mean * scale
// ---------------------------------------------------------------------------
__global__ void stats_kernel(const float* __restrict__ sum, const float* __restrict__ sq,
                             const float* __restrict__ g, const float* __restrict__ beta,
                             float* __restrict__ scale, float* __restrict__ shift,
                             int C, float invM)
{
    int c = blockIdx.x * blockDim.x + threadIdx.x;
    if (c < C) {
        float mean = sum[c] * invM;
        float var  = sq[c] * invM - mean * mean;
        float s = g[c] * rsqrtf(var + 1e-5f);
        scale[c] = s;
        shift[c] = beta[c] - mean * s;
    }
}

// ---------------------------------------------------------------------------
// Kernel 3: GEMM1. A = relu(BN0(y0)) applied on load. Writes pre-BN y1 into
// d_out; accumulates BN1 stats.
// ---------------------------------------------------------------------------
__global__ __launch_bounds__(256) void gemm1_kernel(
    const float* __restrict__ y0,
    const float* __restrict__ scale0, const float* __restrict__ shift0,
    const float* __restrict__ w1, const float* __restrict__ b1,
    float* __restrict__ y1, float* __restrict__ sum1, float* __restrict__ sq1)
{
    __shared__ float As[64][20];
    __shared__ float Bs[64][20];
    __shared__ float red[16][64];
    __shared__ float sc[O0], sh[O0];

    const int t = threadIdx.x;
    const int rowBase = blockIdx.y * 64;
    const int colBase = blockIdx.x * 64;

    sc[t] = scale0[t];
    sh[t] = shift0[t];
    __syncthreads();

    const int tx = t & 15, ty = t >> 4;
    const int ar = t >> 2, ak4 = t & 3;

    const float* arow = y0 + (size_t)(rowBase + ar) * O0;
    const float* wrow = w1 + (size_t)(colBase + ar) * O0;

    float acc[4][4] = {};

    for (int kt = 0; kt < O0; kt += 16) {
        const int kg = kt + ak4 * 4;
        float4 av = *(const float4*)(arow + kg);
        av.x = fmaxf(0.f, av.x * sc[kg + 0] + sh[kg + 0]);
        av.y = fmaxf(0.f, av.y * sc[kg + 1] + sh[kg + 1]);
        av.z = fmaxf(0.f, av.z * sc[kg + 2] + sh[kg + 2]);
        av.w = fmaxf(0.f, av.w * sc[kg + 3] + sh[kg + 3]);
        *(float4*)&As[ar][ak4 * 4] = av;
        *(float4*)&Bs[ar][ak4 * 4] = *(const float4*)(wrow + kg);
        __syncthreads();

        #pragma unroll
        for (int kk = 0; kk < 16; ++kk) {
            float a[4], bb[4];
            #pragma unroll
            for (int i = 0; i < 4; ++i) a[i] = As[ty * 4 + i][kk];
            #pragma unroll
            for (int j = 0; j < 4; ++j) bb[j] = Bs[tx * 4 + j][kk];
            #pragma unroll
            for (int i = 0; i < 4; ++i)
                #pragma unroll
                for (int j = 0; j < 4; ++j) acc[i][j] += a[i] * bb[j];
        }
        __syncthreads();
    }

    float bias[4];
    #pragma unroll
    for (int j = 0; j < 4; ++j) bias[j] = b1[colBase + tx * 4 + j];
    #pragma unroll
    for (int i = 0; i < 4; ++i)
        #pragma unroll
        for (int j = 0; j < 4; ++j) acc[i][j] += bias[j];

    #pragma unroll
    for (int i = 0; i < 4; ++i) {
        int row = rowBase + ty * 4 + i;
        float4 o = make_float4(acc[i][0], acc[i][1], acc[i][2], acc[i][3]);
        *(float4*)(y1 + (size_t)row * O1 + colBase + tx * 4) = o;
    }

    float cs[4], cq[4];
    #pragma unroll
    for (int j = 0; j < 4; ++j) {
        cs[j] = acc[0][j] + acc[1][j] + acc[2][j] + acc[3][j];
        cq[j] = acc[0][j] * acc[0][j] + acc[1][j] * acc[1][j]
              + acc[2][j] * acc[2][j] + acc[3][j] * acc[3][j];
    }
    #pragma unroll
    for (int j = 0; j < 4; ++j) red[ty][tx * 4 + j] = cs[j];
    __syncthreads();
    if (t < 64) {
        float s = 0.f;
        #pragma unroll
        for (int yy = 0; yy < 16; ++yy) s += red[yy][t];
        atomicAdd(&sum1[colBase + t], s);
    }
    __syncthreads();
    #pragma unroll
    for (int j = 0; j < 4; ++j) red[ty][tx * 4 + j] = cq[j];
    __syncthreads();
    if (t < 64) {
        float s = 0.f;
        #pragma unroll
        for (int yy = 0; yy < 16; ++yy) s += red[yy][t];
        atomicAdd(&sq1[colBase + t], s);
    }
}

// ---------------------------------------------------------------------------
// Kernel 4: in-place BN1 + ReLU on d_out (pre-BN y1 -> final output)
// ---------------------------------------------------------------------------
__global__ __launch_bounds__(256) void bn_relu_kernel(
    float* __restrict__ out,
    const float* __restrict__ scale, const float* __restrict__ shift)
{
    int i = blockIdx.x * blockDim.x + threadIdx.x;  // float4 index
    float4 v = ((float4*)out)[i];
    int c = (i * 4) & (O1 - 1);
    v.x = fmaxf(0.f, v.x * scale[c + 0] + shift[c + 0]);
    v.y = fmaxf(0.f, v.y * scale[c + 1] + shift[c + 1]);
    v.z = fmaxf(0.f, v.z * scale[c + 2] + shift[c + 2]);
    v.w = fmaxf(0.f, v.w * scale[c + 3] + shift[c + 3]);
    ((float4*)out)[i] = v;
}

// ---------------------------------------------------------------------------
extern "C" void kernel_launch(void* const* d_in, const int* in_sizes, int n_in,
                              void* d_out, int out_size, void* d_ws, size_t ws_size,
                              hipStream_t stream)
{
    const float* xyz1    = (const float*)d_in[0];
    const float* xyz2    = (const float*)d_in[1];
    const float* points1 = (const float*)d_in[2];
    const float* points2 = (const float*)d_in[3];
    const float* w0      = (const float*)d_in[4];
    const float* b0      = (const float*)d_in[5];
    const float* g0      = (const float*)d_in[6];
    const float* beta0   = (const float*)d_in[7];
    const float* w1      = (const float*)d_in[8];
    const float* b1      = (const float*)d_in[9];
    const float* g1      = (const float*)d_in[10];
    const float* beta1   = (const float*)d_in[11];

    float* wsf = (float*)d_ws;
    // stats block (zeroed each launch)
    float* sum0   = wsf;              // 256
    float* sq0    = wsf + 256;        // 256
    float* sum1   = wsf + 512;        // 128
    float* sq1    = wsf + 640;        // 128
    float* scale0 = wsf + 768;        // 256
    float* shift0 = wsf + 1024;       // 256
    float* scale1 = wsf + 1280;       // 128
    float* shift1 = wsf + 1408;       // 128
    int*   idx3   = (int*)(wsf + 1536);                 // 3*M ints
    float* wgt3   = wsf + 1536 + 3 * MROWS;             // 3*M floats
    float* y0     = wsf + 1536 + 6 * MROWS;             // M*256 floats (16B aligned)

    hipMemsetAsync(d_ws, 0, 768 * sizeof(float), stream);

    nn3_kernel<<<dim3(NPTS / 256, BATCH), 256, 0, stream>>>(xyz1, xyz2, idx3, wgt3);

    gemm0_kernel<<<dim3(O0 / 64, MROWS / 64), 256, 0, stream>>>(
        points1, points2, idx3, wgt3, w0, b0, y0, sum0, sq0);

    stats_kernel<<<1, 256, 0, stream>>>(sum0, sq0, g0, beta0, scale0, shift0,
                                        O0, 1.0f / MROWS);

    gemm1_kernel<<<dim3(O1 / 64, MROWS / 64), 256, 0, stream>>>(
        y0, scale0, shift0, w1, b1, (float*)d_out, sum1, sq1);

    stats_kernel<<<1, 128, 0, stream>>>(sum1, sq1, g1, beta1, scale1, shift1,
                                        O1, 1.0f / MROWS);

    bn_relu_kernel<<<(out_size / 4) / 256, 256, 0, stream>>>(
        (float*)d_out, scale1, shift1);
}

// Round 2
// 320.594 us; speedup vs baseline: 2.4401x; 2.4401x over previous
//
#include <hip/hip_runtime.h>
#include <hip/hip_bf16.h>

// B=8, N=8192, S=2048, D1=128, D2=256, mlp=[256,128], in_ch=384. All fp32 I/O.
#define BATCH 8
#define NPTS  8192
#define SPTS  2048
#define D1C   128
#define D2C   256
#define C_IN  384
#define O0    256
#define O1    128
#define MROWS (BATCH * NPTS)   // 65536

typedef __attribute__((ext_vector_type(8))) short short8v;
typedef __attribute__((ext_vector_type(4))) float f32x4;

__device__ __forceinline__ unsigned short f2bf(float f) {
    union { float f; unsigned u; } v; v.f = f;
    unsigned u = v.u;
    return (unsigned short)((u + 0x7fffu + ((u >> 16) & 1u)) >> 16);  // RNE
}
__device__ __forceinline__ float bf2f(unsigned short h) {
    union { unsigned u; float f; } v; v.u = ((unsigned)h) << 16;
    return v.f;
}
__device__ __forceinline__ void gload_lds16(const void* g, void* l) {
    __builtin_amdgcn_global_load_lds(
        (const __attribute__((address_space(1))) void*)g,
        (__attribute__((address_space(3))) void*)l, 16, 0, 0);
}

// ---------------------------------------------------------------------------
// Kernel 1: 3-NN + inverse-distance weights (unchanged from round 1 - proven).
// ---------------------------------------------------------------------------
__global__ __launch_bounds__(256) void nn3_kernel(
    const float* __restrict__ xyz1, const float* __restrict__ xyz2,
    int* __restrict__ idx3, float* __restrict__ wgt3)
{
    __shared__ float4 P[SPTS];
    const int b = blockIdx.y;
    const int n = blockIdx.x * 256 + threadIdx.x;

    const float* x2 = xyz2 + (size_t)b * SPTS * 3;
    for (int s = threadIdx.x; s < SPTS; s += 256) {
        float px = x2[s * 3 + 0];
        float py = x2[s * 3 + 1];
        float pz = x2[s * 3 + 2];
        P[s] = make_float4(px, py, pz, px * px + py * py + pz * pz);
    }
    __syncthreads();

    const float* q = xyz1 + ((size_t)b * NPTS + n) * 3;
    const float qx = q[0], qy = q[1], qz = q[2];
    const float qn = qx * qx + qy * qy + qz * qz;

    float d0 = 1e30f, d1 = 1e30f, d2 = 1e30f;
    int   i0 = 0,     i1 = 0,     i2 = 0;

    #pragma unroll 4
    for (int s = 0; s < SPTS; ++s) {
        float4 p = P[s];
        float dot = qx * p.x + qy * p.y + qz * p.z;
        float d = (qn + p.w) - 2.0f * dot;
        if (d < d2) {
            if (d < d0)      { d2 = d1; i2 = i1; d1 = d0; i1 = i0; d0 = d; i0 = s; }
            else if (d < d1) { d2 = d1; i2 = i1; d1 = d;  i1 = s; }
            else             { d2 = d;  i2 = s; }
        }
    }

    float wa = 1.0f / (d0 + 1e-8f);
    float wb = 1.0f / (d1 + 1e-8f);
    float wc = 1.0f / (d2 + 1e-8f);
    float inv = 1.0f / (wa + wb + wc);
    wa *= inv; wb *= inv; wc *= inv;

    const int r = b * NPTS + n;
    idx3[r * 3 + 0] = i0;
    idx3[r * 3 + 1] = i1;
    idx3[r * 3 + 2] = i2;
    wgt3[r * 3 + 0] = wa;
    wgt3[r * 3 + 1] = wb;
    wgt3[r * 3 + 2] = wc;
}

// ---------------------------------------------------------------------------
// fp32 -> bf16 weight conversion (n multiple of 4)
// ---------------------------------------------------------------------------
__global__ __launch_bounds__(256) void cvt_f32_bf16(
    const float* __restrict__ src, unsigned short* __restrict__ dst)
{
    int i = blockIdx.x * 256 + threadIdx.x;
    float4 v = ((const float4*)src)[i];
    ushort4 o;
    o.x = f2bf(v.x); o.y = f2bf(v.y); o.z = f2bf(v.z); o.w = f2bf(v.w);
    ((ushort4*)dst)[i] = o;
}

// ---------------------------------------------------------------------------
// GEMM0 (MFMA bf16): y0 = X @ w0^T + b0, X fused on the fly.
// Tile: 128 M x 256 N, BK=32, 512 threads (8 waves, 2x4), 12 K-steps.
// A: reg-staged (points1 cvt / 3-gather interp), B: global_load_lds.
// LDS k-slot swizzle: phys_kslot = log_kslot ^ ((row>>1)&3)  (2-way reads).
// ---------------------------------------------------------------------------
__global__ __launch_bounds__(512) void gemm0_mfma(
    const float* __restrict__ points1, const float* __restrict__ points2,
    const int* __restrict__ idx3, const float* __restrict__ wgt3,
    const unsigned short* __restrict__ w0bf, const float* __restrict__ b0,
    unsigned short* __restrict__ y0bf,
    float* __restrict__ sum0, float* __restrict__ sq0)
{
    __shared__ __align__(16) unsigned short As[128 * 32];   // 8 KB
    __shared__ __align__(16) unsigned short Bs[256 * 32];   // 16 KB

    const int t    = threadIdx.x;
    const int lane = t & 63;
    const int w    = t >> 6;           // wave 0..7
    const int wm   = w >> 2;           // 0..1
    const int wn   = w & 3;            // 0..3
    const int rowBase = blockIdx.x * 128;
    const int b = rowBase >> 13;       // batch (8192 rows per batch, no straddle)

    // ---- A staging identity: thread t -> (row r=t/4, phys kslot t%4)
    const int r      = t >> 2;                      // 0..127
    const int ks_log = (t & 3) ^ ((t >> 3) & 3);    // logical k-slot at this slot
    const int row_g  = rowBase + r;
    const float* p1row = points1 + (size_t)row_g * D1C;
    const float* p2b   = points2 + (size_t)b * SPTS * D2C;
    const int   gi0 = idx3[row_g * 3 + 0];
    const int   gi1 = idx3[row_g * 3 + 1];
    const int   gi2 = idx3[row_g * 3 + 2];
    const float gw0 = wgt3[row_g * 3 + 0];
    const float gw1 = wgt3[row_g * 3 + 1];
    const float gw2 = wgt3[row_g * 3 + 2];
    const float* g0p = p2b + (size_t)gi0 * D2C;
    const float* g1p = p2b + (size_t)gi1 * D2C;
    const float* g2p = p2b + (size_t)gi2 * D2C;
    unsigned short* asw = As + t * 8;   // linear dest, swizzle via source k

    // ---- B staging: 2 x global_load_lds (16B/lane), pre-swizzled source
    const unsigned short* gB0 = w0bf + (size_t)r * C_IN + ks_log * 8;
    const unsigned short* gB1 = w0bf + (size_t)(128 + r) * C_IN + ks_log * 8;
    char* ldsB0 = (char*)Bs + w * 1024;
    char* ldsB1 = (char*)Bs + 8192 + w * 1024;

    // ---- fragment read offsets (swizzled)
    const int rp = (lane & 15) * 64 + (((lane >> 4) ^ ((lane >> 1) & 3)) * 16);
    const char* aBase = (const char*)As + (wm * 64) * 64 + rp;
    const char* bBase = (const char*)Bs + (wn * 64) * 64 + rp;

    f32x4 acc[4][4] = {};

    for (int kt = 0; kt < C_IN / 32; ++kt) {
        // B: async global->LDS
        gload_lds16(gB0 + kt * 32, ldsB0);
        gload_lds16(gB1 + kt * 32, ldsB1);
        // A: reg-staged (cvt / interp)
        const int k = kt * 32 + ks_log * 8;
        float4 f0, f1;
        if (kt * 32 < D1C) {                       // uniform: kt<4 -> points1
            f0 = *(const float4*)(p1row + k);
            f1 = *(const float4*)(p1row + k + 4);
        } else {
            const int k2 = k - D1C;
            float4 A0 = *(const float4*)(g0p + k2);
            float4 A1 = *(const float4*)(g0p + k2 + 4);
            float4 B0 = *(const float4*)(g1p + k2);
            float4 B1 = *(const float4*)(g1p + k2 + 4);
            float4 C0 = *(const float4*)(g2p + k2);
            float4 C1 = *(const float4*)(g2p + k2 + 4);
            f0.x = gw0 * A0.x + gw1 * B0.x + gw2 * C0.x;
            f0.y = gw0 * A0.y + gw1 * B0.y + gw2 * C0.y;
            f0.z = gw0 * A0.z + gw1 * B0.z + gw2 * C0.z;
            f0.w = gw0 * A0.w + gw1 * B0.w + gw2 * C0.w;
            f1.x = gw0 * A1.x + gw1 * B1.x + gw2 * C1.x;
            f1.y = gw0 * A1.y + gw1 * B1.y + gw2 * C1.y;
            f1.z = gw0 * A1.z + gw1 * B1.z + gw2 * C1.z;
            f1.w = gw0 * A1.w + gw1 * B1.w + gw2 * C1.w;
        }
        short8v av;
        av[0] = (short)f2bf(f0.x); av[1] = (short)f2bf(f0.y);
        av[2] = (short)f2bf(f0.z); av[3] = (short)f2bf(f0.w);
        av[4] = (short)f2bf(f1.x); av[5] = (short)f2bf(f1.y);
        av[6] = (short)f2bf(f1.z); av[7] = (short)f2bf(f1.w);
        *(short8v*)asw = av;

        __syncthreads();

        short8v a[4], bf[4];
        #pragma unroll
        for (int m = 0; m < 4; ++m) a[m]  = *(const short8v*)(aBase + m * 1024);
        #pragma unroll
        for (int n = 0; n < 4; ++n) bf[n] = *(const short8v*)(bBase + n * 1024);
        #pragma unroll
        for (int m = 0; m < 4; ++m)
            #pragma unroll
            for (int n = 0; n < 4; ++n)
                acc[m][n] = __builtin_amdgcn_mfma_f32_16x16x32_bf16(
                    a[m], bf[n], acc[m][n], 0, 0, 0);

        __syncthreads();
    }

    // ---- epilogue: bias, bf16 store, BN stats
    const int colw = wn * 64 + (lane & 15);                 // + n*16
    const int rowE = rowBase + wm * 64 + ((lane >> 4) * 4); // + m*16 + j
    float bias[4];
    #pragma unroll
    for (int n = 0; n < 4; ++n) bias[n] = b0[colw + n * 16];

    float cs[4] = {0.f, 0.f, 0.f, 0.f}, cq[4] = {0.f, 0.f, 0.f, 0.f};
    #pragma unroll
    for (int m = 0; m < 4; ++m)
        #pragma unroll
        for (int n = 0; n < 4; ++n)
            #pragma unroll
            for (int j = 0; j < 4; ++j) {
                float v = acc[m][n][j] + bias[n];
                y0bf[(size_t)(rowE + m * 16 + j) * O0 + colw + n * 16] = f2bf(v);
                cs[n] += v; cq[n] += v * v;
            }

    #pragma unroll
    for (int n = 0; n < 4; ++n) {
        float s = cs[n], qv = cq[n];
        s  += __shfl_xor(s, 16);  s  += __shfl_xor(s, 32);
        qv += __shfl_xor(qv, 16); qv += __shfl_xor(qv, 32);
        if (lane < 16) {
            atomicAdd(&sum0[colw + n * 16], s);
            atomicAdd(&sq0[colw + n * 16], qv);
        }
    }
}

// ---------------------------------------------------------------------------
// stats: scale = g * rsqrt(var+eps), shift = beta - mean*scale
// ---------------------------------------------------------------------------
__global__ void stats_kernel(const float* __restrict__ sum, const float* __restrict__ sq,
                             const float* __restrict__ g, const float* __restrict__ beta,
                             float* __restrict__ scale, float* __restrict__ shift,
                             int C, float invM)
{
    int c = blockIdx.x * blockDim.x + threadIdx.x;
    if (c < C) {
        float mean = sum[c] * invM;
        float var  = sq[c] * invM - mean * mean;
        float s = g[c] * rsqrtf(var + 1e-5f);
        scale[c] = s;
        shift[c] = beta[c] - mean * s;
    }
}

// ---------------------------------------------------------------------------
// In-place BN0 + ReLU on y0bf (bf16) -> becomes X1. Deterministic: gemm0
// rewrites y0bf every launch before this runs.
// ---------------------------------------------------------------------------
__global__ __launch_bounds__(256) void bnrelu_bf16_inplace(
    unsigned short* __restrict__ y,
    const float* __restrict__ scale, const float* __restrict__ shift)
{
    int i = blockIdx.x * 256 + threadIdx.x;       // chunk of 8 elems
    short8v v = ((const short8v*)y)[i];
    int c = (i * 8) & (O0 - 1);
    float4 sl = *(const float4*)(scale + c);
    float4 sh = *(const float4*)(scale + c + 4);
    float4 tl = *(const float4*)(shift + c);
    float4 th = *(const float4*)(shift + c + 4);
    short8v o;
    o[0] = (short)f2bf(fmaxf(0.f, bf2f((unsigned short)v[0]) * sl.x + tl.x));
    o[1] = (short)f2bf(fmaxf(0.f, bf2f((unsigned short)v[1]) * sl.y + tl.y));
    o[2] = (short)f2bf(fmaxf(0.f, bf2f((unsigned short)v[2]) * sl.z + tl.z));
    o[3] = (short)f2bf(fmaxf(0.f, bf2f((unsigned short)v[3]) * sl.w + tl.w));
    o[4] = (short)f2bf(fmaxf(0.f, bf2f((unsigned short)v[4]) * sh.x + th.x));
    o[5] = (short)f2bf(fmaxf(0.f, bf2f((unsigned short)v[5]) * sh.y + th.y));
    o[6] = (short)f2bf(fmaxf(0.f, bf2f((unsigned short)v[6]) * sh.z + th.z));
    o[7] = (short)f2bf(fmaxf(0.f, bf2f((unsigned short)v[7]) * sh.w + th.w));
    ((short8v*)y)[i] = o;
}

// ---------------------------------------------------------------------------
// GEMM1 (MFMA bf16): y1 = X1 @ w1^T + b1 -> d_out (fp32, pre-BN) + stats1.
// Tile: 128x128, BK=32, 256 threads (4 waves, 2x2), both sides global_load_lds.
// ---------------------------------------------------------------------------
__global__ __launch_bounds__(256) void gemm1_mfma(
    const unsigned short* __restrict__ x1, const unsigned short* __restrict__ w1bf,
    const float* __restrict__ b1, float* __restrict__ out,
    float* __restrict__ sum1, float* __restrict__ sq1)
{
    __shared__ __align__(16) unsigned short As[128 * 32];   // 8 KB
    __shared__ __align__(16) unsigned short Bs[128 * 32];   // 8 KB

    const int t    = threadIdx.x;
    const int lane = t & 63;
    const int w    = t >> 6;          // 0..3
    const int wm   = w >> 1, wn = w & 1;
    const int rowBase = blockIdx.x * 128;

    const int r      = t >> 2;                     // 0..63
    const int ks_log = (t & 3) ^ ((t >> 3) & 3);

    const unsigned short* gA0 = x1 + (size_t)(rowBase + r) * O0 + ks_log * 8;
    const unsigned short* gA1 = x1 + (size_t)(rowBase + 64 + r) * O0 + ks_log * 8;
    const unsigned short* gB0 = w1bf + (size_t)r * O0 + ks_log * 8;
    const unsigned short* gB1 = w1bf + (size_t)(64 + r) * O0 + ks_log * 8;
    char* ldsA0 = (char*)As + w * 1024;
    char* ldsA1 = (char*)As + 4096 + w * 1024;
    char* ldsB0 = (char*)Bs + w * 1024;
    char* ldsB1 = (char*)Bs + 4096 + w * 1024;

    const int rp = (lane & 15) * 64 + (((lane >> 4) ^ ((lane >> 1) & 3)) * 16);
    const char* aBase = (const char*)As + (wm * 64) * 64 + rp;
    const char* bBase = (const char*)Bs + (wn * 64) * 64 + rp;

    f32x4 acc[4][4] = {};

    for (int kt = 0; kt < O0 / 32; ++kt) {
        gload_lds16(gA0 + kt * 32, ldsA0);
        gload_lds16(gA1 + kt * 32, ldsA1);
        gload_lds16(gB0 + kt * 32, ldsB0);
        gload_lds16(gB1 + kt * 32, ldsB1);

        __syncthreads();

        short8v a[4], bf[4];
        #pragma unroll
        for (int m = 0; m < 4; ++m) a[m]  = *(const short8v*)(aBase + m * 1024);
        #pragma unroll
        for (int n = 0; n < 4; ++n) bf[n] = *(const short8v*)(bBase + n * 1024);
        #pragma unroll
        for (int m = 0; m < 4; ++m)
            #pragma unroll
            for (int n = 0; n < 4; ++n)
                acc[m][n] = __builtin_amdgcn_mfma_f32_16x16x32_bf16(
                    a[m], bf[n], acc[m][n], 0, 0, 0);

        __syncthreads();
    }

    const int colw = wn * 64 + (lane & 15);
    const int rowE = rowBase + wm * 64 + ((lane >> 4) * 4);
    float bias[4];
    #pragma unroll
    for (int n = 0; n < 4; ++n) bias[n] = b1[colw + n * 16];

    float cs[4] = {0.f, 0.f, 0.f, 0.f}, cq[4] = {0.f, 0.f, 0.f, 0.f};
    #pragma unroll
    for (int m = 0; m < 4; ++m)
        #pragma unroll
        for (int n = 0; n < 4; ++n)
            #pragma unroll
            for (int j = 0; j < 4; ++j) {
                float v = acc[m][n][j] + bias[n];
                out[(size_t)(rowE + m * 16 + j) * O1 + colw + n * 16] = v;
                cs[n] += v; cq[n] += v * v;
            }

    #pragma unroll
    for (int n = 0; n < 4; ++n) {
        float s = cs[n], qv = cq[n];
        s  += __shfl_xor(s, 16);  s  += __shfl_xor(s, 32);
        qv += __shfl_xor(qv, 16); qv += __shfl_xor(qv, 32);
        if (lane < 16) {
            atomicAdd(&sum1[colw + n * 16], s);
            atomicAdd(&sq1[colw + n * 16], qv);
        }
    }
}

// ---------------------------------------------------------------------------
// Final in-place BN1 + ReLU on d_out (fp32)
// ---------------------------------------------------------------------------
__global__ __launch_bounds__(256) void bn_relu_kernel(
    float* __restrict__ out,
    const float* __restrict__ scale, const float* __restrict__ shift)
{
    int i = blockIdx.x * blockDim.x + threadIdx.x;  // float4 index
    float4 v = ((float4*)out)[i];
    int c = (i * 4) & (O1 - 1);
    v.x = fmaxf(0.f, v.x * scale[c + 0] + shift[c + 0]);
    v.y = fmaxf(0.f, v.y * scale[c + 1] + shift[c + 1]);
    v.z = fmaxf(0.f, v.z * scale[c + 2] + shift[c + 2]);
    v.w = fmaxf(0.f, v.w * scale[c + 3] + shift[c + 3]);
    ((float4*)out)[i] = v;
}

// ---------------------------------------------------------------------------
extern "C" void kernel_launch(void* const* d_in, const int* in_sizes, int n_in,
                              void* d_out, int out_size, void* d_ws, size_t ws_size,
                              hipStream_t stream)
{
    const float* xyz1    = (const float*)d_in[0];
    const float* xyz2    = (const float*)d_in[1];
    const float* points1 = (const float*)d_in[2];
    const float* points2 = (const float*)d_in[3];
    const float* w0      = (const float*)d_in[4];
    const float* b0      = (const float*)d_in[5];
    const float* g0      = (const float*)d_in[6];
    const float* beta0   = (const float*)d_in[7];
    const float* w1      = (const float*)d_in[8];
    const float* b1      = (const float*)d_in[9];
    const float* g1      = (const float*)d_in[10];
    const float* beta1   = (const float*)d_in[11];

    float* wsf = (float*)d_ws;
    float* sum0   = wsf;              // 256
    float* sq0    = wsf + 256;        // 256
    float* sum1   = wsf + 512;        // 128
    float* sq1    = wsf + 640;        // 128
    float* scale0 = wsf + 768;        // 256
    float* shift0 = wsf + 1024;       // 256
    float* scale1 = wsf + 1280;       // 128
    float* shift1 = wsf + 1408;       // 128
    int*   idx3   = (int*)(wsf + 1536);                       // 3*M ints
    float* wgt3   = wsf + 1536 + 3 * MROWS;                   // 3*M floats
    unsigned short* w0bf = (unsigned short*)(wgt3 + 3 * MROWS);  // 256*384
    unsigned short* w1bf = w0bf + O0 * C_IN;                     // 128*256
    unsigned short* y0bf = w1bf + O1 * O0;                       // M*256 bf16
    // total ws use: ~35.4 MB

    hipMemsetAsync(d_ws, 0, 768 * sizeof(float), stream);

    nn3_kernel<<<dim3(NPTS / 256, BATCH), 256, 0, stream>>>(xyz1, xyz2, idx3, wgt3);

    cvt_f32_bf16<<<(O0 * C_IN / 4) / 256, 256, 0, stream>>>(w0, w0bf);
    cvt_f32_bf16<<<(O1 * O0 / 4) / 256, 256, 0, stream>>>(w1, w1bf);

    gemm0_mfma<<<MROWS / 128, 512, 0, stream>>>(
        points1, points2, idx3, wgt3, w0bf, b0, y0bf, sum0, sq0);

    stats_kernel<<<1, 256, 0, stream>>>(sum0, sq0, g0, beta0, scale0, shift0,
                                        O0, 1.0f / MROWS);

    bnrelu_bf16_inplace<<<(MROWS * O0 / 8) / 256, 256, 0, stream>>>(
        y0bf, scale0, shift0);

    gemm1_mfma<<<MROWS / 128, 256, 0, stream>>>(
        y0bf, w1bf, b1, (float*)d_out, sum1, sq1);

    stats_kernel<<<1, 128, 0, stream>>>(sum1, sq1, g1, beta1, scale1, shift1,
                                        O1, 1.0f / MROWS);

    bn_relu_kernel<<<(out_size / 4) / 256, 256, 0, stream>>>(
        (float*)d_out, scale1, shift1);
}

// Round 3
// 190.614 us; speedup vs baseline: 4.1041x; 1.6819x over previous
//
#include <hip/hip_runtime.h>
#include <hip/hip_bf16.h>

// B=8, N=8192, S=2048, D1=128, D2=256, mlp=[256,128], in_ch=384. All fp32 I/O.
#define BATCH 8
#define NPTS  8192
#define SPTS  2048
#define D1C   128
#define D2C   256
#define C_IN  384
#define O0    256
#define O1    128
#define MROWS (BATCH * NPTS)   // 65536
#define NCHUNK 8
#define CHSZ   256             // SPTS / NCHUNK

typedef __attribute__((ext_vector_type(8))) short short8v;
typedef __attribute__((ext_vector_type(4))) float f32x4;

__device__ __forceinline__ unsigned short f2bf(float f) {
    union { float f; unsigned u; } v; v.f = f;
    unsigned u = v.u;
    return (unsigned short)((u + 0x7fffu + ((u >> 16) & 1u)) >> 16);  // RNE
}
__device__ __forceinline__ float bf2f(unsigned short h) {
    union { unsigned u; float f; } v; v.u = ((unsigned)h) << 16;
    return v.f;
}
__device__ __forceinline__ void gload_lds16(const void* g, void* l) {
    __builtin_amdgcn_global_load_lds(
        (const __attribute__((address_space(1))) void*)g,
        (__attribute__((address_space(3))) void*)l, 16, 0, 0);
}

// ---------------------------------------------------------------------------
// Kernel 1a: chunked 3-NN scan. block = 256 queries x one 256-point chunk.
// Branchless top-3 (fmed3/fmin for distances, cndmask for indices).
// 2048 blocks -> 8 blocks/CU -> full occupancy.
// ---------------------------------------------------------------------------
__global__ __launch_bounds__(256, 8) void nn3_scan(
    const float* __restrict__ xyz1, const float* __restrict__ xyz2,
    float* __restrict__ candD, int* __restrict__ candI)
{
    __shared__ float4 P[CHSZ];
    const int t  = threadIdx.x;
    const int qb = blockIdx.x;        // 0..255 (query block, row-major over B*N)
    const int c  = blockIdx.y;        // chunk 0..7
    const int b  = qb >> 5;           // batch

    // stage chunk points (+ precomputed |p|^2)
    {
        const float* src = xyz2 + ((size_t)b * SPTS + c * CHSZ) * 3;
        float px = src[t * 3 + 0];
        float py = src[t * 3 + 1];
        float pz = src[t * 3 + 2];
        P[t] = make_float4(px, py, pz, px * px + py * py + pz * pz);
    }
    __syncthreads();

    const int q = qb * 256 + t;       // global row (b*NPTS + n)
    const float* qp = xyz1 + (size_t)q * 3;
    const float qx = qp[0], qy = qp[1], qz = qp[2];
    const float qn = qx * qx + qy * qy + qz * qz;

    float d0 = 1e30f, d1 = 1e30f, d2 = 1e30f;
    int   i0 = 0,     i1 = 0,     i2 = 0;
    const int gbase = c * CHSZ;

    #pragma unroll 4
    for (int s = 0; s < CHSZ; ++s) {
        float4 p = P[s];
        float dot = qx * p.x + qy * p.y + qz * p.z;
        float d = (qn + p.w) - 2.0f * dot;     // same formula as reference
        bool c0 = d < d0, c1 = d < d1, c2 = d < d2;
        int gi = gbase + s;
        float t2 = __builtin_amdgcn_fmed3f(d, d1, d2);
        float t1 = __builtin_amdgcn_fmed3f(d, d0, d1);
        i2 = c1 ? i1 : (c2 ? gi : i2);
        i1 = c0 ? i0 : (c1 ? gi : i1);
        i0 = c0 ? gi : i0;
        d2 = t2; d1 = t1; d0 = fminf(d, d0);
    }

    const size_t base = (size_t)c * (MROWS * 3) + (size_t)q * 3;
    candD[base + 0] = d0; candD[base + 1] = d1; candD[base + 2] = d2;
    candI[base + 0] = i0; candI[base + 1] = i1; candI[base + 2] = i2;
}

// ---------------------------------------------------------------------------
// Kernel 1b: merge 8 chunk-candidates -> final top-3 + inverse-distance wgts.
// Insertion in (chunk asc, slot asc) order with strict < preserves the
// reference's lowest-index-first tie-break.
// ---------------------------------------------------------------------------
__global__ __launch_bounds__(256) void nn3_merge(
    const float* __restrict__ candD, const int* __restrict__ candI,
    int* __restrict__ idx3, float* __restrict__ wgt3)
{
    const int q = blockIdx.x * 256 + threadIdx.x;

    float d0 = 1e30f, d1 = 1e30f, d2 = 1e30f;
    int   i0 = 0,     i1 = 0,     i2 = 0;

    #pragma unroll
    for (int c = 0; c < NCHUNK; ++c) {
        const size_t base = (size_t)c * (MROWS * 3) + (size_t)q * 3;
        #pragma unroll
        for (int j = 0; j < 3; ++j) {
            float d = candD[base + j];
            int  gi = candI[base + j];
            bool c0 = d < d0, c1 = d < d1, c2 = d < d2;
            float t2 = __builtin_amdgcn_fmed3f(d, d1, d2);
            float t1 = __builtin_amdgcn_fmed3f(d, d0, d1);
            i2 = c1 ? i1 : (c2 ? gi : i2);
            i1 = c0 ? i0 : (c1 ? gi : i1);
            i0 = c0 ? gi : i0;
            d2 = t2; d1 = t1; d0 = fminf(d, d0);
        }
    }

    float wa = 1.0f / (d0 + 1e-8f);
    float wb = 1.0f / (d1 + 1e-8f);
    float wc = 1.0f / (d2 + 1e-8f);
    float inv = 1.0f / (wa + wb + wc);
    wa *= inv; wb *= inv; wc *= inv;

    idx3[q * 3 + 0] = i0;
    idx3[q * 3 + 1] = i1;
    idx3[q * 3 + 2] = i2;
    wgt3[q * 3 + 0] = wa;
    wgt3[q * 3 + 1] = wb;
    wgt3[q * 3 + 2] = wc;
}

// ---------------------------------------------------------------------------
// fp32 -> bf16 weight conversion (n multiple of 4)
// ---------------------------------------------------------------------------
__global__ __launch_bounds__(256) void cvt_f32_bf16(
    const float* __restrict__ src, unsigned short* __restrict__ dst)
{
    int i = blockIdx.x * 256 + threadIdx.x;
    float4 v = ((const float4*)src)[i];
    ushort4 o;
    o.x = f2bf(v.x); o.y = f2bf(v.y); o.z = f2bf(v.z); o.w = f2bf(v.w);
    ((ushort4*)dst)[i] = o;
}

// ---------------------------------------------------------------------------
// GEMM0 (MFMA bf16): y0 = X @ w0^T + b0, X fused on the fly. (proven, r2)
// Tile: 128 M x 256 N, BK=32, 512 threads (8 waves, 2x4), 12 K-steps.
// ---------------------------------------------------------------------------
__global__ __launch_bounds__(512) void gemm0_mfma(
    const float* __restrict__ points1, const float* __restrict__ points2,
    const int* __restrict__ idx3, const float* __restrict__ wgt3,
    const unsigned short* __restrict__ w0bf, const float* __restrict__ b0,
    unsigned short* __restrict__ y0bf,
    float* __restrict__ sum0, float* __restrict__ sq0)
{
    __shared__ __align__(16) unsigned short As[128 * 32];   // 8 KB
    __shared__ __align__(16) unsigned short Bs[256 * 32];   // 16 KB

    const int t    = threadIdx.x;
    const int lane = t & 63;
    const int w    = t >> 6;           // wave 0..7
    const int wm   = w >> 2;           // 0..1
    const int wn   = w & 3;            // 0..3
    const int rowBase = blockIdx.x * 128;
    const int b = rowBase >> 13;       // batch

    const int r      = t >> 2;                      // 0..127
    const int ks_log = (t & 3) ^ ((t >> 3) & 3);    // logical k-slot here
    const int row_g  = rowBase + r;
    const float* p1row = points1 + (size_t)row_g * D1C;
    const float* p2b   = points2 + (size_t)b * SPTS * D2C;
    const int   gi0 = idx3[row_g * 3 + 0];
    const int   gi1 = idx3[row_g * 3 + 1];
    const int   gi2 = idx3[row_g * 3 + 2];
    const float gw0 = wgt3[row_g * 3 + 0];
    const float gw1 = wgt3[row_g * 3 + 1];
    const float gw2 = wgt3[row_g * 3 + 2];
    const float* g0p = p2b + (size_t)gi0 * D2C;
    const float* g1p = p2b + (size_t)gi1 * D2C;
    const float* g2p = p2b + (size_t)gi2 * D2C;
    unsigned short* asw = As + t * 8;

    const unsigned short* gB0 = w0bf + (size_t)r * C_IN + ks_log * 8;
    const unsigned short* gB1 = w0bf + (size_t)(128 + r) * C_IN + ks_log * 8;
    char* ldsB0 = (char*)Bs + w * 1024;
    char* ldsB1 = (char*)Bs + 8192 + w * 1024;

    const int rp = (lane & 15) * 64 + (((lane >> 4) ^ ((lane >> 1) & 3)) * 16);
    const char* aBase = (const char*)As + (wm * 64) * 64 + rp;
    const char* bBase = (const char*)Bs + (wn * 64) * 64 + rp;

    f32x4 acc[4][4] = {};

    for (int kt = 0; kt < C_IN / 32; ++kt) {
        gload_lds16(gB0 + kt * 32, ldsB0);
        gload_lds16(gB1 + kt * 32, ldsB1);
        const int k = kt * 32 + ks_log * 8;
        float4 f0, f1;
        if (kt * 32 < D1C) {
            f0 = *(const float4*)(p1row + k);
            f1 = *(const float4*)(p1row + k + 4);
        } else {
            const int k2 = k - D1C;
            float4 A0 = *(const float4*)(g0p + k2);
            float4 A1 = *(const float4*)(g0p + k2 + 4);
            float4 B0 = *(const float4*)(g1p + k2);
            float4 B1 = *(const float4*)(g1p + k2 + 4);
            float4 C0 = *(const float4*)(g2p + k2);
            float4 C1 = *(const float4*)(g2p + k2 + 4);
            f0.x = gw0 * A0.x + gw1 * B0.x + gw2 * C0.x;
            f0.y = gw0 * A0.y + gw1 * B0.y + gw2 * C0.y;
            f0.z = gw0 * A0.z + gw1 * B0.z + gw2 * C0.z;
            f0.w = gw0 * A0.w + gw1 * B0.w + gw2 * C0.w;
            f1.x = gw0 * A1.x + gw1 * B1.x + gw2 * C1.x;
            f1.y = gw0 * A1.y + gw1 * B1.y + gw2 * C1.y;
            f1.z = gw0 * A1.z + gw1 * B1.z + gw2 * C1.z;
            f1.w = gw0 * A1.w + gw1 * B1.w + gw2 * C1.w;
        }
        short8v av;
        av[0] = (short)f2bf(f0.x); av[1] = (short)f2bf(f0.y);
        av[2] = (short)f2bf(f0.z); av[3] = (short)f2bf(f0.w);
        av[4] = (short)f2bf(f1.x); av[5] = (short)f2bf(f1.y);
        av[6] = (short)f2bf(f1.z); av[7] = (short)f2bf(f1.w);
        *(short8v*)asw = av;

        __syncthreads();

        short8v a[4], bf[4];
        #pragma unroll
        for (int m = 0; m < 4; ++m) a[m]  = *(const short8v*)(aBase + m * 1024);
        #pragma unroll
        for (int n = 0; n < 4; ++n) bf[n] = *(const short8v*)(bBase + n * 1024);
        #pragma unroll
        for (int m = 0; m < 4; ++m)
            #pragma unroll
            for (int n = 0; n < 4; ++n)
                acc[m][n] = __builtin_amdgcn_mfma_f32_16x16x32_bf16(
                    a[m], bf[n], acc[m][n], 0, 0, 0);

        __syncthreads();
    }

    const int colw = wn * 64 + (lane & 15);
    const int rowE = rowBase + wm * 64 + ((lane >> 4) * 4);
    float bias[4];
    #pragma unroll
    for (int n = 0; n < 4; ++n) bias[n] = b0[colw + n * 16];

    float cs[4] = {0.f, 0.f, 0.f, 0.f}, cq[4] = {0.f, 0.f, 0.f, 0.f};
    #pragma unroll
    for (int m = 0; m < 4; ++m)
        #pragma unroll
        for (int n = 0; n < 4; ++n)
            #pragma unroll
            for (int j = 0; j < 4; ++j) {
                float v = acc[m][n][j] + bias[n];
                y0bf[(size_t)(rowE + m * 16 + j) * O0 + colw + n * 16] = f2bf(v);
                cs[n] += v; cq[n] += v * v;
            }

    #pragma unroll
    for (int n = 0; n < 4; ++n) {
        float s = cs[n], qv = cq[n];
        s  += __shfl_xor(s, 16);  s  += __shfl_xor(s, 32);
        qv += __shfl_xor(qv, 16); qv += __shfl_xor(qv, 32);
        if (lane < 16) {
            atomicAdd(&sum0[colw + n * 16], s);
            atomicAdd(&sq0[colw + n * 16], qv);
        }
    }
}

// ---------------------------------------------------------------------------
// stats: scale = g * rsqrt(var+eps), shift = beta - mean*scale
// ---------------------------------------------------------------------------
__global__ void stats_kernel(const float* __restrict__ sum, const float* __restrict__ sq,
                             const float* __restrict__ g, const float* __restrict__ beta,
                             float* __restrict__ scale, float* __restrict__ shift,
                             int C, float invM)
{
    int c = blockIdx.x * blockDim.x + threadIdx.x;
    if (c < C) {
        float mean = sum[c] * invM;
        float var  = sq[c] * invM - mean * mean;
        float s = g[c] * rsqrtf(var + 1e-5f);
        scale[c] = s;
        shift[c] = beta[c] - mean * s;
    }
}

// ---------------------------------------------------------------------------
// GEMM1 (MFMA bf16) with FUSED BN0+ReLU on the A operand.
// A: reg-staged (load pre-BN bf16 y0, apply scale/shift+relu, ds_write
// swizzled). B: global_load_lds (pre-swizzled source). Writes pre-BN y1 fp32
// to d_out + BN1 stats.
// ---------------------------------------------------------------------------
__global__ __launch_bounds__(256) void gemm1_mfma(
    const unsigned short* __restrict__ x1, const unsigned short* __restrict__ w1bf,
    const float* __restrict__ scale0, const float* __restrict__ shift0,
    const float* __restrict__ b1, float* __restrict__ out,
    float* __restrict__ sum1, float* __restrict__ sq1)
{
    __shared__ __align__(16) unsigned short As[128 * 32];   // 8 KB
    __shared__ __align__(16) unsigned short Bs[128 * 32];   // 8 KB
    __shared__ float sc[O0], sh[O0];

    const int t    = threadIdx.x;
    const int lane = t & 63;
    const int w    = t >> 6;          // 0..3
    const int wm   = w >> 1, wn = w & 1;
    const int rowBase = blockIdx.x * 128;

    sc[t] = scale0[t];
    sh[t] = shift0[t];
    __syncthreads();

    const int r      = t >> 2;                     // 0..63
    const int kl     = t & 3;                      // logical k-slot (A path)
    const int kp     = kl ^ ((r >> 1) & 3);        // phys k-slot (A path)
    const int ks_log = kl ^ ((r >> 1) & 3);        // B path: same function

    const unsigned short* gA0 = x1 + (size_t)(rowBase + r) * O0 + kl * 8;
    const unsigned short* gA1 = x1 + (size_t)(rowBase + 64 + r) * O0 + kl * 8;
    unsigned short* dA0 = As + r * 32 + kp * 8;
    unsigned short* dA1 = As + (64 + r) * 32 + kp * 8;

    const unsigned short* gB0 = w1bf + (size_t)r * O0 + ks_log * 8;
    const unsigned short* gB1 = w1bf + (size_t)(64 + r) * O0 + ks_log * 8;
    char* ldsB0 = (char*)Bs + w * 1024;
    char* ldsB1 = (char*)Bs + 4096 + w * 1024;

    const int rp = (lane & 15) * 64 + (((lane >> 4) ^ ((lane >> 1) & 3)) * 16);
    const char* aBase = (const char*)As + (wm * 64) * 64 + rp;
    const char* bBase = (const char*)Bs + (wn * 64) * 64 + rp;

    f32x4 acc[4][4] = {};

    for (int kt = 0; kt < O0 / 32; ++kt) {
        // B: async global -> LDS
        gload_lds16(gB0 + kt * 32, ldsB0);
        gload_lds16(gB1 + kt * 32, ldsB1);

        // A: reg-staged with BN0 + ReLU
        const int ch = kt * 32 + kl * 8;
        float4 s0v = *(const float4*)(sc + ch);
        float4 s1v = *(const float4*)(sc + ch + 4);
        float4 h0v = *(const float4*)(sh + ch);
        float4 h1v = *(const float4*)(sh + ch + 4);
        short8v v0 = *(const short8v*)(gA0 + kt * 32);
        short8v v1 = *(const short8v*)(gA1 + kt * 32);
        short8v o0, o1;
        o0[0] = (short)f2bf(fmaxf(0.f, bf2f((unsigned short)v0[0]) * s0v.x + h0v.x));
        o0[1] = (short)f2bf(fmaxf(0.f, bf2f((unsigned short)v0[1]) * s0v.y + h0v.y));
        o0[2] = (short)f2bf(fmaxf(0.f, bf2f((unsigned short)v0[2]) * s0v.z + h0v.z));
        o0[3] = (short)f2bf(fmaxf(0.f, bf2f((unsigned short)v0[3]) * s0v.w + h0v.w));
        o0[4] = (short)f2bf(fmaxf(0.f, bf2f((unsigned short)v0[4]) * s1v.x + h1v.x));
        o0[5] = (short)f2bf(fmaxf(0.f, bf2f((unsigned short)v0[5]) * s1v.y + h1v.y));
        o0[6] = (short)f2bf(fmaxf(0.f, bf2f((unsigned short)v0[6]) * s1v.z + h1v.z));
        o0[7] = (short)f2bf(fmaxf(0.f, bf2f((unsigned short)v0[7]) * s1v.w + h1v.w));
        o1[0] = (short)f2bf(fmaxf(0.f, bf2f((unsigned short)v1[0]) * s0v.x + h0v.x));
        o1[1] = (short)f2bf(fmaxf(0.f, bf2f((unsigned short)v1[1]) * s0v.y + h0v.y));
        o1[2] = (short)f2bf(fmaxf(0.f, bf2f((unsigned short)v1[2]) * s0v.z + h0v.z));
        o1[3] = (short)f2bf(fmaxf(0.f, bf2f((unsigned short)v1[3]) * s0v.w + h0v.w));
        o1[4] = (short)f2bf(fmaxf(0.f, bf2f((unsigned short)v1[4]) * s1v.x + h1v.x));
        o1[5] = (short)f2bf(fmaxf(0.f, bf2f((unsigned short)v1[5]) * s1v.y + h1v.y));
        o1[6] = (short)f2bf(fmaxf(0.f, bf2f((unsigned short)v1[6]) * s1v.z + h1v.z));
        o1[7] = (short)f2bf(fmaxf(0.f, bf2f((unsigned short)v1[7]) * s1v.w + h1v.w));
        *(short8v*)dA0 = o0;
        *(short8v*)dA1 = o1;

        __syncthreads();

        short8v a[4], bf[4];
        #pragma unroll
        for (int m = 0; m < 4; ++m) a[m]  = *(const short8v*)(aBase + m * 1024);
        #pragma unroll
        for (int n = 0; n < 4; ++n) bf[n] = *(const short8v*)(bBase + n * 1024);
        #pragma unroll
        for (int m = 0; m < 4; ++m)
            #pragma unroll
            for (int n = 0; n < 4; ++n)
                acc[m][n] = __builtin_amdgcn_mfma_f32_16x16x32_bf16(
                    a[m], bf[n], acc[m][n], 0, 0, 0);

        __syncthreads();
    }

    const int colw = wn * 64 + (lane & 15);
    const int rowE = rowBase + wm * 64 + ((lane >> 4) * 4);
    float bias[4];
    #pragma unroll
    for (int n = 0; n < 4; ++n) bias[n] = b1[colw + n * 16];

    float cs[4] = {0.f, 0.f, 0.f, 0.f}, cq[4] = {0.f, 0.f, 0.f, 0.f};
    #pragma unroll
    for (int m = 0; m < 4; ++m)
        #pragma unroll
        for (int n = 0; n < 4; ++n)
            #pragma unroll
            for (int j = 0; j < 4; ++j) {
                float v = acc[m][n][j] + bias[n];
                out[(size_t)(rowE + m * 16 + j) * O1 + colw + n * 16] = v;
                cs[n] += v; cq[n] += v * v;
            }

    #pragma unroll
    for (int n = 0; n < 4; ++n) {
        float s = cs[n], qv = cq[n];
        s  += __shfl_xor(s, 16);  s  += __shfl_xor(s, 32);
        qv += __shfl_xor(qv, 16); qv += __shfl_xor(qv, 32);
        if (lane < 16) {
            atomicAdd(&sum1[colw + n * 16], s);
            atomicAdd(&sq1[colw + n * 16], qv);
        }
    }
}

// ---------------------------------------------------------------------------
// Final in-place BN1 + ReLU on d_out (fp32)
// ---------------------------------------------------------------------------
__global__ __launch_bounds__(256) void bn_relu_kernel(
    float* __restrict__ out,
    const float* __restrict__ scale, const float* __restrict__ shift)
{
    int i = blockIdx.x * blockDim.x + threadIdx.x;  // float4 index
    float4 v = ((float4*)out)[i];
    int c = (i * 4) & (O1 - 1);
    v.x = fmaxf(0.f, v.x * scale[c + 0] + shift[c + 0]);
    v.y = fmaxf(0.f, v.y * scale[c + 1] + shift[c + 1]);
    v.z = fmaxf(0.f, v.z * scale[c + 2] + shift[c + 2]);
    v.w = fmaxf(0.f, v.w * scale[c + 3] + shift[c + 3]);
    ((float4*)out)[i] = v;
}

// ---------------------------------------------------------------------------
extern "C" void kernel_launch(void* const* d_in, const int* in_sizes, int n_in,
                              void* d_out, int out_size, void* d_ws, size_t ws_size,
                              hipStream_t stream)
{
    const float* xyz1    = (const float*)d_in[0];
    const float* xyz2    = (const float*)d_in[1];
    const float* points1 = (const float*)d_in[2];
    const float* points2 = (const float*)d_in[3];
    const float* w0      = (const float*)d_in[4];
    const float* b0      = (const float*)d_in[5];
    const float* g0      = (const float*)d_in[6];
    const float* beta0   = (const float*)d_in[7];
    const float* w1      = (const float*)d_in[8];
    const float* b1      = (const float*)d_in[9];
    const float* g1      = (const float*)d_in[10];
    const float* beta1   = (const float*)d_in[11];

    float* wsf = (float*)d_ws;
    float* sum0   = wsf;              // 256
    float* sq0    = wsf + 256;        // 256
    float* sum1   = wsf + 512;        // 128
    float* sq1    = wsf + 640;        // 128
    float* scale0 = wsf + 768;        // 256
    float* shift0 = wsf + 1024;       // 256
    float* scale1 = wsf + 1280;       // 128
    float* shift1 = wsf + 1408;       // 128
    int*   idx3   = (int*)(wsf + 1536);                       // 3*M ints
    float* wgt3   = wsf + 1536 + 3 * MROWS;                   // 3*M floats
    float* candD  = wgt3 + 3 * MROWS;                         // 24*M floats
    int*   candI  = (int*)(candD + 3 * NCHUNK * MROWS);       // 24*M ints
    unsigned short* w0bf = (unsigned short*)(candI + 3 * NCHUNK * MROWS);
    unsigned short* w1bf = w0bf + O0 * C_IN;
    unsigned short* y0bf = w1bf + O1 * O0;                    // M*256 bf16
    // total ws use: ~48 MB

    hipMemsetAsync(d_ws, 0, 768 * sizeof(float), stream);

    nn3_scan<<<dim3(MROWS / 256, NCHUNK), 256, 0, stream>>>(xyz1, xyz2, candD, candI);
    nn3_merge<<<MROWS / 256, 256, 0, stream>>>(candD, candI, idx3, wgt3);

    cvt_f32_bf16<<<(O0 * C_IN / 4) / 256, 256, 0, stream>>>(w0, w0bf);
    cvt_f32_bf16<<<(O1 * O0 / 4) / 256, 256, 0, stream>>>(w1, w1bf);

    gemm0_mfma<<<MROWS / 128, 512, 0, stream>>>(
        points1, points2, idx3, wgt3, w0bf, b0, y0bf, sum0, sq0);

    stats_kernel<<<1, 256, 0, stream>>>(sum0, sq0, g0, beta0, scale0, shift0,
                                        O0, 1.0f / MROWS);

    gemm1_mfma<<<MROWS / 128, 256, 0, stream>>>(
        y0bf, w1bf, scale0, shift0, b1, (float*)d_out, sum1, sq1);

    stats_kernel<<<1, 128, 0, stream>>>(sum1, sq1, g1, beta1, scale1, shift1,
                                        O1, 1.0f / MROWS);

    bn_relu_kernel<<<(out_size / 4) / 256, 256, 0, stream>>>(
        (float*)d_out, scale1, shift1);
}